// Round 1
// baseline (792.131 us; speedup 1.0000x reference)
//
#include <hip/hip_runtime.h>

#define NF 128

// ---------------------------------------------------------------------------
// K1: edge-parallel degree count (int atomics, cheap: 1.6M atomics total)
// ---------------------------------------------------------------------------
__global__ __launch_bounds__(256) void deg_kernel(const int* __restrict__ src,
                                                  const int* __restrict__ dst,
                                                  int* __restrict__ deg_out,
                                                  int* __restrict__ deg_in,
                                                  int n_edges) {
    int i = blockIdx.x * 256 + threadIdx.x;
    if (i < n_edges) {
        atomicAdd(&deg_out[src[i]], 1);
        atomicAdd(&deg_in[dst[i]], 1);
    }
}

// ---------------------------------------------------------------------------
// K2: per-node norm = (max(deg_in,1) * max(deg_out,1))^-1/2   (alpha=beta=0.5)
// ---------------------------------------------------------------------------
__global__ __launch_bounds__(256) void norm_kernel(const int* __restrict__ deg_out,
                                                   const int* __restrict__ deg_in,
                                                   float* __restrict__ norm, int n) {
    int i = blockIdx.x * 256 + threadIdx.x;
    if (i < n) {
        int dov = deg_out[i]; if (dov < 1) dov = 1;
        int div_ = deg_in[i]; if (div_ < 1) div_ = 1;
        norm[i] = 1.0f / sqrtf((float)dov * (float)div_);
    }
}

// ---------------------------------------------------------------------------
// K3: edge-parallel scatter-aggregate. One wave per edge; each lane handles a
// float2 (64 lanes x 8B = 512B row). feat gather is L2/L3-resident (25.6MB).
// rst[dst] accumulated via f32 global atomics (102.4M total) — expected
// bottleneck this round; CSR-gather planned if confirmed.
// ---------------------------------------------------------------------------
__global__ __launch_bounds__(256) void scatter_kernel(const float* __restrict__ feat,
                                                      const float* __restrict__ norm,
                                                      const int* __restrict__ src,
                                                      const int* __restrict__ dst,
                                                      float* __restrict__ rst,
                                                      int n_edges) {
    int wid = (blockIdx.x * 256 + threadIdx.x) >> 6;   // global wave id = edge id
    int lane = threadIdx.x & 63;
    if (wid >= n_edges) return;
    int s = src[wid];
    int d = dst[wid];
    float nv = norm[s];
    float2 v = ((const float2*)(feat + (size_t)s * NF))[lane];
    float* rp = rst + (size_t)d * NF + lane * 2;
    atomicAdd(rp,     v.x * nv);
    atomicAdd(rp + 1, v.y * nv);
}

// ---------------------------------------------------------------------------
// K4: out = relu(rst @ W + bias). f32 vector-ALU GEMM (no fp32 MFMA on CDNA4).
// W staged in LDS (128x132 padded, 67.6KB -> 2 blocks/CU). 16 rows/block,
// each thread: 1 row x 8 cols, k-loop broadcast of rst[row][k].
// ---------------------------------------------------------------------------
__global__ __launch_bounds__(256) void gemm_kernel(const float* __restrict__ rst,
                                                   const float* __restrict__ W,
                                                   const float* __restrict__ bias,
                                                   float* __restrict__ out,
                                                   int n_nodes) {
    __shared__ float Wlds[NF][NF + 4];
    for (int i = threadIdx.x; i < NF * NF; i += 256) {
        Wlds[i >> 7][i & 127] = W[i];
    }
    __syncthreads();
    int cg = threadIdx.x & 15;    // col group: 8 consecutive cols
    int rl = threadIdx.x >> 4;    // local row 0..15
    int row = blockIdx.x * 16 + rl;
    if (row >= n_nodes) return;
    const float* rrow = rst + (size_t)row * NF;
    float acc[8];
#pragma unroll
    for (int j = 0; j < 8; ++j) acc[j] = 0.0f;
#pragma unroll 8
    for (int k = 0; k < NF; ++k) {
        float a = rrow[k];                 // same addr across 16 threads: broadcast
        const float* wp = &Wlds[k][cg * 8];
#pragma unroll
        for (int j = 0; j < 8; ++j) acc[j] += a * wp[j];
    }
    float* op = out + (size_t)row * NF + cg * 8;
#pragma unroll
    for (int j = 0; j < 8; ++j) {
        float v = acc[j] + bias[cg * 8 + j];
        op[j] = v > 0.0f ? v : 0.0f;
    }
}

extern "C" void kernel_launch(void* const* d_in, const int* in_sizes, int n_in,
                              void* d_out, int out_size, void* d_ws, size_t ws_size,
                              hipStream_t stream) {
    const float* feat = (const float*)d_in[0];
    const float* W    = (const float*)d_in[1];
    const float* bias = (const float*)d_in[2];
    const int*   src  = (const int*)d_in[3];
    const int*   dst  = (const int*)d_in[4];

    int n_nodes = in_sizes[0] / NF;
    int n_edges = in_sizes[3];

    // workspace layout: [rst: n*128 f32][deg_out: n i32][deg_in: n i32][norm: n f32]
    char* ws = (char*)d_ws;
    size_t rst_bytes = (size_t)n_nodes * NF * sizeof(float);
    float* rst     = (float*)ws;
    int*   deg_out = (int*)(ws + rst_bytes);
    int*   deg_in  = deg_out + n_nodes;
    float* norm    = (float*)(deg_in + n_nodes);

    // zero rst + both degree arrays (norm is fully overwritten)
    hipMemsetAsync(d_ws, 0, rst_bytes + 2 * (size_t)n_nodes * sizeof(int), stream);

    deg_kernel<<<(n_edges + 255) / 256, 256, 0, stream>>>(src, dst, deg_out, deg_in, n_edges);
    norm_kernel<<<(n_nodes + 255) / 256, 256, 0, stream>>>(deg_out, deg_in, norm, n_nodes);
    // one wave per edge, 4 edges per 256-thread block
    scatter_kernel<<<(n_edges + 3) / 4, 256, 0, stream>>>(feat, norm, src, dst, rst, n_edges);
    gemm_kernel<<<(n_nodes + 15) / 16, 256, 0, stream>>>(rst, W, bias, (float*)d_out, n_nodes);
}

// Round 2
// 354.051 us; speedup vs baseline: 2.2373x; 2.2373x over previous
//
#include <hip/hip_runtime.h>

#define NF 128

// ---------------------------------------------------------------------------
// K1: edge-parallel degree count (int atomics, cheap)
// ---------------------------------------------------------------------------
__global__ __launch_bounds__(256) void deg_kernel(const int* __restrict__ src,
                                                  const int* __restrict__ dst,
                                                  int* __restrict__ deg_out,
                                                  int* __restrict__ deg_in,
                                                  int n_edges) {
    int i = blockIdx.x * 256 + threadIdx.x;
    if (i < n_edges) {
        atomicAdd(&deg_out[src[i]], 1);
        atomicAdd(&deg_in[dst[i]], 1);
    }
}

// ---------------------------------------------------------------------------
// K2: per-node norm = (max(deg_in,1) * max(deg_out,1))^-1/2
// ---------------------------------------------------------------------------
__global__ __launch_bounds__(256) void norm_kernel(const int* __restrict__ deg_out,
                                                   const int* __restrict__ deg_in,
                                                   float* __restrict__ norm, int n) {
    int i = blockIdx.x * 256 + threadIdx.x;
    if (i < n) {
        int dov = deg_out[i]; if (dov < 1) dov = 1;
        int div_ = deg_in[i]; if (div_ < 1) div_ = 1;
        norm[i] = 1.0f / sqrtf((float)dov * (float)div_);
    }
}

// ---------------------------------------------------------------------------
// K3: single-block exclusive scan of deg_in -> start[] and cursor[] (copy).
// 1024 threads, Hillis-Steele per 1024-chunk with running carry. n=50K -> 49
// chunks, trivial time.
// ---------------------------------------------------------------------------
__global__ __launch_bounds__(1024) void scan_kernel(const int* __restrict__ deg,
                                                    int* __restrict__ start,
                                                    int* __restrict__ cursor, int n) {
    __shared__ int sdata[1024];
    __shared__ int carry_s;
    if (threadIdx.x == 0) carry_s = 0;
    __syncthreads();
    for (int base = 0; base < n; base += 1024) {
        int i = base + (int)threadIdx.x;
        int v = (i < n) ? deg[i] : 0;
        sdata[threadIdx.x] = v;
        __syncthreads();
        for (int off = 1; off < 1024; off <<= 1) {
            int t = (threadIdx.x >= (unsigned)off) ? sdata[threadIdx.x - off] : 0;
            __syncthreads();
            sdata[threadIdx.x] += t;
            __syncthreads();
        }
        int excl = sdata[threadIdx.x] - v + carry_s;   // carry_s read before update
        if (i < n) { start[i] = excl; cursor[i] = excl; }
        __syncthreads();
        if (threadIdx.x == 1023) carry_s += sdata[1023];
        __syncthreads();
    }
}

// ---------------------------------------------------------------------------
// K4: CSR fill. pos = atomicAdd(cursor[dst]) gives the global slot directly
// (cursor starts at segment start). After this kernel, cursor[d] = segment end.
// ---------------------------------------------------------------------------
__global__ __launch_bounds__(256) void fill_kernel(const int* __restrict__ src,
                                                   const int* __restrict__ dst,
                                                   int* __restrict__ cursor,
                                                   int* __restrict__ csr_src,
                                                   int n_edges) {
    int e = blockIdx.x * 256 + threadIdx.x;
    if (e < n_edges) {
        int d = dst[e];
        int pos = atomicAdd(&cursor[d], 1);
        csr_src[pos] = src[e];
    }
}

// ---------------------------------------------------------------------------
// K5: gather-aggregate. One wave per dst node; lane holds a float2 of the
// 128-float row. Per edge: uniform csr_src/norm loads (broadcast), coalesced
// 512B feat row read (L2/L3-resident), register FMA. Single 512B store.
// No float atomics anywhere.
// ---------------------------------------------------------------------------
__global__ __launch_bounds__(256) void gather_kernel(const float* __restrict__ feat,
                                                     const float* __restrict__ norm,
                                                     const int* __restrict__ csr_src,
                                                     const int* __restrict__ start,
                                                     const int* __restrict__ endp,
                                                     float* __restrict__ rst,
                                                     int n_nodes) {
    int wid  = (blockIdx.x * 256 + threadIdx.x) >> 6;
    int lane = threadIdx.x & 63;
    if (wid >= n_nodes) return;
    int beg = start[wid];
    int end = endp[wid];           // cursor after fill = segment end
    float2 acc = make_float2(0.0f, 0.0f);
    for (int i = beg; i < end; ++i) {
        int s = csr_src[i];
        float nv = norm[s];
        float2 v = ((const float2*)(feat + (size_t)s * NF))[lane];
        acc.x = fmaf(v.x, nv, acc.x);
        acc.y = fmaf(v.y, nv, acc.y);
    }
    ((float2*)(rst + (size_t)wid * NF))[lane] = acc;
}

// ---------------------------------------------------------------------------
// K6: out = relu(rst @ W + bias). f32 vector-ALU GEMM, W staged in LDS.
// 16 rows/block, thread = 1 row x 8 cols; rrow loaded as float4 (4 k's/load).
// ---------------------------------------------------------------------------
__global__ __launch_bounds__(256) void gemm_kernel(const float* __restrict__ rst,
                                                   const float* __restrict__ W,
                                                   const float* __restrict__ bias,
                                                   float* __restrict__ out,
                                                   int n_nodes) {
    __shared__ float Wlds[NF][NF + 4];
    for (int i = threadIdx.x; i < NF * NF; i += 256) {
        Wlds[i >> 7][i & 127] = W[i];
    }
    __syncthreads();
    int cg = threadIdx.x & 15;    // col group: 8 consecutive cols
    int rl = threadIdx.x >> 4;    // local row 0..15
    int row = blockIdx.x * 16 + rl;
    if (row >= n_nodes) return;
    const float* rrow = rst + (size_t)row * NF;
    float acc[8];
#pragma unroll
    for (int j = 0; j < 8; ++j) acc[j] = 0.0f;
#pragma unroll 4
    for (int k = 0; k < NF; k += 4) {
        float4 a = *(const float4*)(rrow + k);
#pragma unroll
        for (int kk = 0; kk < 4; ++kk) {
            float av = (kk == 0) ? a.x : (kk == 1) ? a.y : (kk == 2) ? a.z : a.w;
            const float* wp = &Wlds[k + kk][cg * 8];
#pragma unroll
            for (int j = 0; j < 8; ++j) acc[j] = fmaf(av, wp[j], acc[j]);
        }
    }
    float* op = out + (size_t)row * NF + cg * 8;
#pragma unroll
    for (int j = 0; j < 8; ++j) {
        float v = acc[j] + bias[cg * 8 + j];
        op[j] = v > 0.0f ? v : 0.0f;
    }
}

extern "C" void kernel_launch(void* const* d_in, const int* in_sizes, int n_in,
                              void* d_out, int out_size, void* d_ws, size_t ws_size,
                              hipStream_t stream) {
    const float* feat = (const float*)d_in[0];
    const float* W    = (const float*)d_in[1];
    const float* bias = (const float*)d_in[2];
    const int*   src  = (const int*)d_in[3];
    const int*   dst  = (const int*)d_in[4];

    int n_nodes = in_sizes[0] / NF;
    int n_edges = in_sizes[3];

    // ws layout: [rst n*128 f32][deg_out n][deg_in n][norm n f32][start n][cursor n][csr_src E]
    char* ws = (char*)d_ws;
    size_t rst_bytes = (size_t)n_nodes * NF * sizeof(float);
    float* rst     = (float*)ws;
    int*   deg_out = (int*)(ws + rst_bytes);
    int*   deg_in  = deg_out + n_nodes;
    float* norm    = (float*)(deg_in + n_nodes);
    int*   start   = (int*)(norm + n_nodes);
    int*   cursor  = start + n_nodes;
    int*   csr_src = cursor + n_nodes;

    // zero only the degree arrays (everything else fully overwritten)
    hipMemsetAsync(deg_out, 0, 2 * (size_t)n_nodes * sizeof(int), stream);

    deg_kernel<<<(n_edges + 255) / 256, 256, 0, stream>>>(src, dst, deg_out, deg_in, n_edges);
    norm_kernel<<<(n_nodes + 255) / 256, 256, 0, stream>>>(deg_out, deg_in, norm, n_nodes);
    scan_kernel<<<1, 1024, 0, stream>>>(deg_in, start, cursor, n_nodes);
    fill_kernel<<<(n_edges + 255) / 256, 256, 0, stream>>>(src, dst, cursor, csr_src, n_edges);
    gather_kernel<<<(n_nodes * 64 + 255) / 256, 256, 0, stream>>>(feat, norm, csr_src, start,
                                                                  cursor, rst, n_nodes);
    gemm_kernel<<<(n_nodes + 15) / 16, 256, 0, stream>>>(rst, W, bias, (float*)d_out, n_nodes);
}

// Round 3
// 272.509 us; speedup vs baseline: 2.9068x; 1.2992x over previous
//
#include <hip/hip_runtime.h>

#define NF 128

// ---------------------------------------------------------------------------
// K1: edge-parallel degree count (int atomics, cheap)
// ---------------------------------------------------------------------------
__global__ __launch_bounds__(256) void deg_kernel(const int* __restrict__ src,
                                                  const int* __restrict__ dst,
                                                  int* __restrict__ deg_out,
                                                  int* __restrict__ deg_in,
                                                  int n_edges) {
    int i = blockIdx.x * 256 + threadIdx.x;
    if (i < n_edges) {
        atomicAdd(&deg_out[src[i]], 1);
        atomicAdd(&deg_in[dst[i]], 1);
    }
}

// ---------------------------------------------------------------------------
// K2: per-node norm = (max(deg_in,1) * max(deg_out,1))^-1/2
// ---------------------------------------------------------------------------
__global__ __launch_bounds__(256) void norm_kernel(const int* __restrict__ deg_out,
                                                   const int* __restrict__ deg_in,
                                                   float* __restrict__ norm, int n) {
    int i = blockIdx.x * 256 + threadIdx.x;
    if (i < n) {
        int dov = deg_out[i]; if (dov < 1) dov = 1;
        int div_ = deg_in[i]; if (div_ < 1) div_ = 1;
        norm[i] = 1.0f / sqrtf((float)dov * (float)div_);
    }
}

// ---------------------------------------------------------------------------
// Three-phase parallel exclusive scan of deg_in (n=50K, 49 chunks of 1024).
// Replaces the 95us single-block scan (0.18% occupancy) with ~10us total.
// ---------------------------------------------------------------------------
// Phase 1: per-block sum -> bsum[b]
__global__ __launch_bounds__(1024) void scan_sum_kernel(const int* __restrict__ deg,
                                                        int* __restrict__ bsum, int n) {
    int i = blockIdx.x * 1024 + threadIdx.x;
    int v = (i < n) ? deg[i] : 0;
#pragma unroll
    for (int off = 32; off >= 1; off >>= 1) v += __shfl_down(v, off, 64);
    __shared__ int ws[16];
    int wv = threadIdx.x >> 6, lane = threadIdx.x & 63;
    if (lane == 0) ws[wv] = v;
    __syncthreads();
    if (threadIdx.x == 0) {
        int s = 0;
#pragma unroll
        for (int k = 0; k < 16; ++k) s += ws[k];
        bsum[blockIdx.x] = s;
    }
}

// Phase 2: single block exclusive-scans bsum in place (nb <= 1024)
__global__ __launch_bounds__(1024) void scan_bsum_kernel(int* __restrict__ bsum, int nb) {
    __shared__ int s[1024];
    int v = (threadIdx.x < (unsigned)nb) ? bsum[threadIdx.x] : 0;
    s[threadIdx.x] = v;
    __syncthreads();
    for (int off = 1; off < 1024; off <<= 1) {
        int t = (threadIdx.x >= (unsigned)off) ? s[threadIdx.x - off] : 0;
        __syncthreads();
        s[threadIdx.x] += t;
        __syncthreads();
    }
    if (threadIdx.x < (unsigned)nb) bsum[threadIdx.x] = s[threadIdx.x] - v;  // exclusive
}

// Phase 3: per-block scan + bsum offset -> start[], cursor[]
__global__ __launch_bounds__(1024) void scan_final_kernel(const int* __restrict__ deg,
                                                          const int* __restrict__ bsum,
                                                          int* __restrict__ start,
                                                          int* __restrict__ cursor, int n) {
    int i = blockIdx.x * 1024 + threadIdx.x;
    int v = (i < n) ? deg[i] : 0;
    int lane = threadIdx.x & 63, wv = threadIdx.x >> 6;
    int incl = v;
#pragma unroll
    for (int off = 1; off < 64; off <<= 1) {
        int t = __shfl_up(incl, off, 64);
        if (lane >= off) incl += t;
    }
    __shared__ int ws[16];
    __shared__ int wo[16];
    if (lane == 63) ws[wv] = incl;
    __syncthreads();
    if (threadIdx.x == 0) {
        int s = 0;
#pragma unroll
        for (int k = 0; k < 16; ++k) { wo[k] = s; s += ws[k]; }
    }
    __syncthreads();
    int excl = incl - v + wo[wv] + bsum[blockIdx.x];
    if (i < n) { start[i] = excl; cursor[i] = excl; }
}

// ---------------------------------------------------------------------------
// K4: CSR fill. pos = atomicAdd(cursor[dst]); cursor[d] ends at segment end.
// ---------------------------------------------------------------------------
__global__ __launch_bounds__(256) void fill_kernel(const int* __restrict__ src,
                                                   const int* __restrict__ dst,
                                                   int* __restrict__ cursor,
                                                   int* __restrict__ csr_src,
                                                   int n_edges) {
    int e = blockIdx.x * 256 + threadIdx.x;
    if (e < n_edges) {
        int d = dst[e];
        int pos = atomicAdd(&cursor[d], 1);
        csr_src[pos] = src[e];
    }
}

// ---------------------------------------------------------------------------
// K5: gather-aggregate. One wave per dst node; lane holds a float2.
// ---------------------------------------------------------------------------
__global__ __launch_bounds__(256) void gather_kernel(const float* __restrict__ feat,
                                                     const float* __restrict__ norm,
                                                     const int* __restrict__ csr_src,
                                                     const int* __restrict__ start,
                                                     const int* __restrict__ endp,
                                                     float* __restrict__ rst,
                                                     int n_nodes) {
    int wid  = (blockIdx.x * 256 + threadIdx.x) >> 6;
    int lane = threadIdx.x & 63;
    if (wid >= n_nodes) return;
    int beg = start[wid];
    int end = endp[wid];
    float2 acc = make_float2(0.0f, 0.0f);
    for (int i = beg; i < end; ++i) {
        int s = csr_src[i];
        float nv = norm[s];
        float2 v = ((const float2*)(feat + (size_t)s * NF))[lane];
        acc.x = fmaf(v.x, nv, acc.x);
        acc.y = fmaf(v.y, nv, acc.y);
    }
    ((float2*)(rst + (size_t)wid * NF))[lane] = acc;
}

// ---------------------------------------------------------------------------
// K6: out = relu(rst @ W + bias). f32 vector-ALU GEMM, W staged in LDS.
// ---------------------------------------------------------------------------
__global__ __launch_bounds__(256) void gemm_kernel(const float* __restrict__ rst,
                                                   const float* __restrict__ W,
                                                   const float* __restrict__ bias,
                                                   float* __restrict__ out,
                                                   int n_nodes) {
    __shared__ float Wlds[NF][NF + 4];
    for (int i = threadIdx.x; i < NF * NF; i += 256) {
        Wlds[i >> 7][i & 127] = W[i];
    }
    __syncthreads();
    int cg = threadIdx.x & 15;    // col group: 8 consecutive cols
    int rl = threadIdx.x >> 4;    // local row 0..15
    int row = blockIdx.x * 16 + rl;
    if (row >= n_nodes) return;
    const float* rrow = rst + (size_t)row * NF;
    float acc[8];
#pragma unroll
    for (int j = 0; j < 8; ++j) acc[j] = 0.0f;
#pragma unroll 4
    for (int k = 0; k < NF; k += 4) {
        float4 a = *(const float4*)(rrow + k);
#pragma unroll
        for (int kk = 0; kk < 4; ++kk) {
            float av = (kk == 0) ? a.x : (kk == 1) ? a.y : (kk == 2) ? a.z : a.w;
            const float* wp = &Wlds[k + kk][cg * 8];
#pragma unroll
            for (int j = 0; j < 8; ++j) acc[j] = fmaf(av, wp[j], acc[j]);
        }
    }
    float* op = out + (size_t)row * NF + cg * 8;
#pragma unroll
    for (int j = 0; j < 8; ++j) {
        float v = acc[j] + bias[cg * 8 + j];
        op[j] = v > 0.0f ? v : 0.0f;
    }
}

extern "C" void kernel_launch(void* const* d_in, const int* in_sizes, int n_in,
                              void* d_out, int out_size, void* d_ws, size_t ws_size,
                              hipStream_t stream) {
    const float* feat = (const float*)d_in[0];
    const float* W    = (const float*)d_in[1];
    const float* bias = (const float*)d_in[2];
    const int*   src  = (const int*)d_in[3];
    const int*   dst  = (const int*)d_in[4];

    int n_nodes = in_sizes[0] / NF;
    int n_edges = in_sizes[3];

    // ws: [rst n*128 f32][deg_out n][deg_in n][norm n f32][start n][cursor n][bsum 1024][csr_src E]
    char* ws = (char*)d_ws;
    size_t rst_bytes = (size_t)n_nodes * NF * sizeof(float);
    float* rst     = (float*)ws;
    int*   deg_out = (int*)(ws + rst_bytes);
    int*   deg_in  = deg_out + n_nodes;
    float* norm    = (float*)(deg_in + n_nodes);
    int*   start   = (int*)(norm + n_nodes);
    int*   cursor  = start + n_nodes;
    int*   bsum    = cursor + n_nodes;
    int*   csr_src = bsum + 1024;

    hipMemsetAsync(deg_out, 0, 2 * (size_t)n_nodes * sizeof(int), stream);

    deg_kernel<<<(n_edges + 255) / 256, 256, 0, stream>>>(src, dst, deg_out, deg_in, n_edges);
    norm_kernel<<<(n_nodes + 255) / 256, 256, 0, stream>>>(deg_out, deg_in, norm, n_nodes);

    int nb = (n_nodes + 1023) / 1024;   // 49 for n=50K (must be <= 1024)
    scan_sum_kernel<<<nb, 1024, 0, stream>>>(deg_in, bsum, n_nodes);
    scan_bsum_kernel<<<1, 1024, 0, stream>>>(bsum, nb);
    scan_final_kernel<<<nb, 1024, 0, stream>>>(deg_in, bsum, start, cursor, n_nodes);

    fill_kernel<<<(n_edges + 255) / 256, 256, 0, stream>>>(src, dst, cursor, csr_src, n_edges);
    gather_kernel<<<(n_nodes * 64 + 255) / 256, 256, 0, stream>>>(feat, norm, csr_src, start,
                                                                  cursor, rst, n_nodes);
    gemm_kernel<<<(n_nodes + 15) / 16, 256, 0, stream>>>(rst, W, bias, (float*)d_out, n_nodes);
}

// Round 4
// 209.116 us; speedup vs baseline: 3.7880x; 1.3031x over previous
//
#include <hip/hip_runtime.h>

#define NF 128

typedef __attribute__((ext_vector_type(8))) short short8;   // 8 x bf16 (4 VGPRs)
typedef __attribute__((ext_vector_type(4))) float f32x4;
typedef unsigned int uint;
typedef unsigned short ushort;

// round-to-nearest-even f32 -> bf16 (finite inputs; deterministic, no lib deps)
__device__ __forceinline__ ushort f2bf(float f) {
    uint u = __float_as_uint(f);
    uint r = (u + 0x7fffu + ((u >> 16) & 1u)) >> 16;
    return (ushort)r;
}
__device__ __forceinline__ float bflo(uint v) { return __uint_as_float(v << 16); }
__device__ __forceinline__ float bfhi(uint v) { return __uint_as_float(v & 0xffff0000u); }

// ---------------------------------------------------------------------------
// K1: edge-parallel degree count
// ---------------------------------------------------------------------------
__global__ __launch_bounds__(256) void deg_kernel(const int* __restrict__ src,
                                                  const int* __restrict__ dst,
                                                  int* __restrict__ deg_out,
                                                  int* __restrict__ deg_in,
                                                  int n_edges) {
    int i = blockIdx.x * 256 + threadIdx.x;
    if (i < n_edges) {
        atomicAdd(&deg_out[src[i]], 1);
        atomicAdd(&deg_in[dst[i]], 1);
    }
}

// ---------------------------------------------------------------------------
// K2: norm = (max(deg_in,1)*max(deg_out,1))^-1/2
// ---------------------------------------------------------------------------
__global__ __launch_bounds__(256) void norm_kernel(const int* __restrict__ deg_out,
                                                   const int* __restrict__ deg_in,
                                                   float* __restrict__ norm, int n) {
    int i = blockIdx.x * 256 + threadIdx.x;
    if (i < n) {
        int dov = deg_out[i]; if (dov < 1) dov = 1;
        int div_ = deg_in[i]; if (div_ < 1) div_ = 1;
        norm[i] = 1.0f / sqrtf((float)dov * (float)div_);
    }
}

// ---------------------------------------------------------------------------
// K3: featn[node][c] = bf16(feat[node][c] * norm[node]), packed 2/uint32.
// One-time 38 MB pass; removes norm load+mul from gather and halves its bytes.
// ---------------------------------------------------------------------------
__global__ __launch_bounds__(256) void featn_kernel(const float* __restrict__ feat,
                                                    const float* __restrict__ norm,
                                                    uint* __restrict__ featn, int total) {
    int idx = blockIdx.x * 256 + threadIdx.x;
    if (idx >= total) return;
    int node = idx >> 6;                 // 64 uint32 per 128-feat row
    float nv = norm[node];
    float2 v = ((const float2*)feat)[idx];
    featn[idx] = (uint)f2bf(v.x * nv) | ((uint)f2bf(v.y * nv) << 16);
}

// ---------------------------------------------------------------------------
// K4: W^T in bf16: wt[n*128+k] = bf16(W[k][n]). 8192 uint32, one-time.
// ---------------------------------------------------------------------------
__global__ __launch_bounds__(256) void wt_kernel(const float* __restrict__ W,
                                                 uint* __restrict__ wt) {
    int idx = blockIdx.x * 256 + threadIdx.x;
    if (idx >= NF * NF / 2) return;
    int nrow = idx >> 6;
    int k2 = idx & 63;
    float a = W[(2 * k2) * NF + nrow];
    float b = W[(2 * k2 + 1) * NF + nrow];
    wt[idx] = (uint)f2bf(a) | ((uint)f2bf(b) << 16);
}

// ---------------------------------------------------------------------------
// Three-phase parallel exclusive scan of deg_in
// ---------------------------------------------------------------------------
__global__ __launch_bounds__(1024) void scan_sum_kernel(const int* __restrict__ deg,
                                                        int* __restrict__ bsum, int n) {
    int i = blockIdx.x * 1024 + threadIdx.x;
    int v = (i < n) ? deg[i] : 0;
#pragma unroll
    for (int off = 32; off >= 1; off >>= 1) v += __shfl_down(v, off, 64);
    __shared__ int ws[16];
    int wv = threadIdx.x >> 6, lane = threadIdx.x & 63;
    if (lane == 0) ws[wv] = v;
    __syncthreads();
    if (threadIdx.x == 0) {
        int s = 0;
#pragma unroll
        for (int k = 0; k < 16; ++k) s += ws[k];
        bsum[blockIdx.x] = s;
    }
}

__global__ __launch_bounds__(1024) void scan_bsum_kernel(int* __restrict__ bsum, int nb) {
    __shared__ int s[1024];
    int v = (threadIdx.x < (unsigned)nb) ? bsum[threadIdx.x] : 0;
    s[threadIdx.x] = v;
    __syncthreads();
    for (int off = 1; off < 1024; off <<= 1) {
        int t = (threadIdx.x >= (unsigned)off) ? s[threadIdx.x - off] : 0;
        __syncthreads();
        s[threadIdx.x] += t;
        __syncthreads();
    }
    if (threadIdx.x < (unsigned)nb) bsum[threadIdx.x] = s[threadIdx.x] - v;
}

__global__ __launch_bounds__(1024) void scan_final_kernel(const int* __restrict__ deg,
                                                          const int* __restrict__ bsum,
                                                          int* __restrict__ start,
                                                          int* __restrict__ cursor, int n) {
    int i = blockIdx.x * 1024 + threadIdx.x;
    int v = (i < n) ? deg[i] : 0;
    int lane = threadIdx.x & 63, wv = threadIdx.x >> 6;
    int incl = v;
#pragma unroll
    for (int off = 1; off < 64; off <<= 1) {
        int t = __shfl_up(incl, off, 64);
        if (lane >= off) incl += t;
    }
    __shared__ int ws[16];
    __shared__ int wo[16];
    if (lane == 63) ws[wv] = incl;
    __syncthreads();
    if (threadIdx.x == 0) {
        int s = 0;
#pragma unroll
        for (int k = 0; k < 16; ++k) { wo[k] = s; s += ws[k]; }
    }
    __syncthreads();
    int excl = incl - v + wo[wv] + bsum[blockIdx.x];
    if (i < n) { start[i] = excl; cursor[i] = excl; }
}

// ---------------------------------------------------------------------------
// K5: CSR fill
// ---------------------------------------------------------------------------
__global__ __launch_bounds__(256) void fill_kernel(const int* __restrict__ src,
                                                   const int* __restrict__ dst,
                                                   int* __restrict__ cursor,
                                                   int* __restrict__ csr_src,
                                                   int n_edges) {
    int e = blockIdx.x * 256 + threadIdx.x;
    if (e < n_edges) {
        int d = dst[e];
        int pos = atomicAdd(&cursor[d], 1);
        csr_src[pos] = src[e];
    }
}

// ---------------------------------------------------------------------------
// K6: gather-aggregate (bf16). One wave per dst node; lane holds one uint32
// (2 bf16). 256B/edge row reads; unroll-2 keeps two loads in flight.
// Output rst as bf16 (MFMA A operand).
// ---------------------------------------------------------------------------
__global__ __launch_bounds__(256) void gather_kernel(const uint* __restrict__ featn,
                                                     const int* __restrict__ csr_src,
                                                     const int* __restrict__ start,
                                                     const int* __restrict__ endp,
                                                     uint* __restrict__ rst_h,
                                                     int n_nodes) {
    int wid  = (blockIdx.x * 256 + threadIdx.x) >> 6;
    int lane = threadIdx.x & 63;
    if (wid >= n_nodes) return;
    int beg = start[wid];
    int end = endp[wid];
    float ax = 0.0f, ay = 0.0f;
    int i = beg;
    for (; i + 1 < end; i += 2) {
        int s0 = csr_src[i];
        int s1 = csr_src[i + 1];
        uint v0 = featn[(size_t)s0 * 64 + lane];
        uint v1 = featn[(size_t)s1 * 64 + lane];
        ax += bflo(v0); ay += bfhi(v0);
        ax += bflo(v1); ay += bfhi(v1);
    }
    if (i < end) {
        int s = csr_src[i];
        uint v = featn[(size_t)s * 64 + lane];
        ax += bflo(v); ay += bfhi(v);
    }
    rst_h[(size_t)wid * 64 + lane] = (uint)f2bf(ax) | ((uint)f2bf(ay) << 16);
}

// ---------------------------------------------------------------------------
// K7: out = relu(rst_h @ W + bias) via mfma_f32_16x16x32_bf16.
// Block = 4 waves x 16 rows = 64 rows. B read directly from W^T bf16 (32KB,
// L1/L2-resident) — no LDS. A frags: lane row=l&15, k=8*(l>>4)+j (contig 16B).
// C/D: col=l&15, row=(l>>4)*4+r (measured m89 mapping).
// ---------------------------------------------------------------------------
__global__ __launch_bounds__(256) void gemm_mfma_kernel(const ushort* __restrict__ rst_h,
                                                        const ushort* __restrict__ wt_h,
                                                        const float* __restrict__ bias,
                                                        float* __restrict__ out,
                                                        int n_nodes) {
    int wave = threadIdx.x >> 6;
    int lane = threadIdx.x & 63;
    int row0 = blockIdx.x * 64 + wave * 16;
    if (row0 >= n_nodes) return;         // wave-uniform tail skip
    int l16 = lane & 15, lq = lane >> 4;

    // A fragments for all 4 K-tiles (overread past n lands in featn ws region)
    short8 a[4];
    const ushort* ap = rst_h + (size_t)(row0 + l16) * NF + lq * 8;
#pragma unroll
    for (int kt = 0; kt < 4; ++kt) a[kt] = *(const short8*)(ap + kt * 32);

#pragma unroll
    for (int nt = 0; nt < 8; ++nt) {
        f32x4 acc = {0.0f, 0.0f, 0.0f, 0.0f};
        const ushort* bp = wt_h + (size_t)(nt * 16 + l16) * NF + lq * 8;
#pragma unroll
        for (int kt = 0; kt < 4; ++kt) {
            short8 b = *(const short8*)(bp + kt * 32);
            acc = __builtin_amdgcn_mfma_f32_16x16x32_bf16(a[kt], b, acc, 0, 0, 0);
        }
        int col = nt * 16 + l16;
        float bv = bias[col];
#pragma unroll
        for (int r = 0; r < 4; ++r) {
            int orow = row0 + lq * 4 + r;
            if (orow < n_nodes) {
                float v = acc[r] + bv;
                out[(size_t)orow * NF + col] = v > 0.0f ? v : 0.0f;
            }
        }
    }
}

extern "C" void kernel_launch(void* const* d_in, const int* in_sizes, int n_in,
                              void* d_out, int out_size, void* d_ws, size_t ws_size,
                              hipStream_t stream) {
    const float* feat = (const float*)d_in[0];
    const float* W    = (const float*)d_in[1];
    const float* bias = (const float*)d_in[2];
    const int*   src  = (const int*)d_in[3];
    const int*   dst  = (const int*)d_in[4];

    int n_nodes = in_sizes[0] / NF;
    int n_edges = in_sizes[3];

    // ws: [rst_h n*64 u32][featn n*64 u32][deg_out n][deg_in n][norm n f32]
    //     [start n][cursor n][bsum 1024][wt 8192 u32][csr_src E]
    char* ws = (char*)d_ws;
    size_t row_u32 = (size_t)n_nodes * 64;
    uint*  rst_h   = (uint*)ws;
    uint*  featn   = rst_h + row_u32;
    int*   deg_out = (int*)(featn + row_u32);
    int*   deg_in  = deg_out + n_nodes;
    float* norm    = (float*)(deg_in + n_nodes);
    int*   start   = (int*)(norm + n_nodes);
    int*   cursor  = start + n_nodes;
    int*   bsum    = cursor + n_nodes;
    uint*  wt      = (uint*)(bsum + 1024);
    int*   csr_src = (int*)(wt + NF * NF / 2);

    hipMemsetAsync(deg_out, 0, 2 * (size_t)n_nodes * sizeof(int), stream);

    deg_kernel<<<(n_edges + 255) / 256, 256, 0, stream>>>(src, dst, deg_out, deg_in, n_edges);
    norm_kernel<<<(n_nodes + 255) / 256, 256, 0, stream>>>(deg_out, deg_in, norm, n_nodes);

    int total_pairs = n_nodes * 64;
    featn_kernel<<<(total_pairs + 255) / 256, 256, 0, stream>>>(feat, norm, featn, total_pairs);
    wt_kernel<<<(NF * NF / 2 + 255) / 256, 256, 0, stream>>>(W, wt);

    int nb = (n_nodes + 1023) / 1024;
    scan_sum_kernel<<<nb, 1024, 0, stream>>>(deg_in, bsum, n_nodes);
    scan_bsum_kernel<<<1, 1024, 0, stream>>>(bsum, nb);
    scan_final_kernel<<<nb, 1024, 0, stream>>>(deg_in, bsum, start, cursor, n_nodes);

    fill_kernel<<<(n_edges + 255) / 256, 256, 0, stream>>>(src, dst, cursor, csr_src, n_edges);
    gather_kernel<<<(n_nodes * 64 + 255) / 256, 256, 0, stream>>>(featn, csr_src, start,
                                                                  cursor, rst_h, n_nodes);
    gemm_mfma_kernel<<<(n_nodes + 63) / 64, 256, 0, stream>>>((const ushort*)rst_h,
                                                              (const ushort*)wt, bias,
                                                              (float*)d_out, n_nodes);
}

// Round 5
// 152.380 us; speedup vs baseline: 5.1984x; 1.3723x over previous
//
#include <hip/hip_runtime.h>

#define NF 128
#define NCHUNK 64          // edge chunks for histogram/counting passes
#define HIST_THREADS 512
#define NNW_MAX 25088      // max packed u16-pair words in LDS (100.3 KB); n_nodes <= 50176

typedef __attribute__((ext_vector_type(8))) short short8;   // 8 x bf16 (4 VGPRs)
typedef __attribute__((ext_vector_type(4))) float f32x4;
typedef unsigned int uint;
typedef unsigned short ushort;

// round-to-nearest-even f32 -> bf16
__device__ __forceinline__ ushort f2bf(float f) {
    uint u = __float_as_uint(f);
    uint r = (u + 0x7fffu + ((u >> 16) & 1u)) >> 16;
    return (ushort)r;
}
__device__ __forceinline__ float bflo(uint v) { return __uint_as_float(v << 16); }
__device__ __forceinline__ float bfhi(uint v) { return __uint_as_float(v & 0xffff0000u); }

// ---------------------------------------------------------------------------
// K1: LDS-privatized degree histograms — NO global atomics.
// grid (NCHUNK, 2): y=0 counts dst (deg_in), y=1 counts src (deg_out).
// Each block: full-node histogram in LDS, packed 2 x u16 per u32 (chunk edge
// count 12.5K < 2^16 => low half can never carry into high half). Dumps a
// per-chunk partial (u32 words) for the reduce kernel.
// ---------------------------------------------------------------------------
__global__ __launch_bounds__(HIST_THREADS) void hist_kernel(const int* __restrict__ src,
                                                            const int* __restrict__ dst,
                                                            uint* __restrict__ partial_in,
                                                            uint* __restrict__ partial_out,
                                                            int n_edges, int nwords, int epb) {
    __shared__ uint h[NNW_MAX];
    for (int w = threadIdx.x; w < nwords; w += HIST_THREADS) h[w] = 0;
    __syncthreads();
    const int* idx = blockIdx.y ? src : dst;
    int ebeg = blockIdx.x * epb;
    int eend = min(ebeg + epb, n_edges);
    for (int e = ebeg + (int)threadIdx.x; e < eend; e += HIST_THREADS) {
        int node = idx[e];
        atomicAdd(&h[node >> 1], 1u << ((node & 1) * 16));
    }
    __syncthreads();
    uint* p = (blockIdx.y ? partial_out : partial_in) + (size_t)blockIdx.x * nwords;
    for (int w = threadIdx.x; w < nwords; w += HIST_THREADS) p[w] = h[w];
}

// ---------------------------------------------------------------------------
// K2: reduce partials -> deg_in[] (for scan) + fused norm[].
// One thread per packed word (2 nodes).
// ---------------------------------------------------------------------------
__global__ __launch_bounds__(256) void degnorm_kernel(const uint* __restrict__ partial_in,
                                                      const uint* __restrict__ partial_out,
                                                      int* __restrict__ deg_in,
                                                      float* __restrict__ norm,
                                                      int nwords, int n) {
    int w = blockIdx.x * 256 + threadIdx.x;
    if (w >= nwords) return;
    uint si0 = 0, si1 = 0, so0 = 0, so1 = 0;
#pragma unroll 4
    for (int c = 0; c < NCHUNK; ++c) {
        uint vi = partial_in[(size_t)c * nwords + w];
        uint vo = partial_out[(size_t)c * nwords + w];
        si0 += vi & 0xffffu; si1 += vi >> 16;
        so0 += vo & 0xffffu; so1 += vo >> 16;
    }
    int n0 = 2 * w, n1 = 2 * w + 1;
    {
        uint di = si0 < 1u ? 1u : si0, dv = so0 < 1u ? 1u : so0;
        deg_in[n0] = (int)si0;
        norm[n0] = 1.0f / sqrtf((float)di * (float)dv);
    }
    if (n1 < n) {
        uint di = si1 < 1u ? 1u : si1, dv = so1 < 1u ? 1u : so1;
        deg_in[n1] = (int)si1;
        norm[n1] = 1.0f / sqrtf((float)di * (float)dv);
    }
}

// ---------------------------------------------------------------------------
// Fallback (n_nodes too big for LDS histogram): original atomic path
// ---------------------------------------------------------------------------
__global__ __launch_bounds__(256) void deg_kernel(const int* __restrict__ src,
                                                  const int* __restrict__ dst,
                                                  int* __restrict__ deg_out,
                                                  int* __restrict__ deg_in,
                                                  int n_edges) {
    int i = blockIdx.x * 256 + threadIdx.x;
    if (i < n_edges) {
        atomicAdd(&deg_out[src[i]], 1);
        atomicAdd(&deg_in[dst[i]], 1);
    }
}
__global__ __launch_bounds__(256) void norm_kernel(const int* __restrict__ deg_out,
                                                   const int* __restrict__ deg_in,
                                                   float* __restrict__ norm, int n) {
    int i = blockIdx.x * 256 + threadIdx.x;
    if (i < n) {
        int dov = deg_out[i]; if (dov < 1) dov = 1;
        int div_ = deg_in[i]; if (div_ < 1) div_ = 1;
        norm[i] = 1.0f / sqrtf((float)dov * (float)div_);
    }
}

// ---------------------------------------------------------------------------
// K3: featn = bf16(feat * norm[node]), packed 2/u32
// ---------------------------------------------------------------------------
__global__ __launch_bounds__(256) void featn_kernel(const float* __restrict__ feat,
                                                    const float* __restrict__ norm,
                                                    uint* __restrict__ featn, int total) {
    int idx = blockIdx.x * 256 + threadIdx.x;
    if (idx >= total) return;
    int node = idx >> 6;
    float nv = norm[node];
    float2 v = ((const float2*)feat)[idx];
    featn[idx] = (uint)f2bf(v.x * nv) | ((uint)f2bf(v.y * nv) << 16);
}

// ---------------------------------------------------------------------------
// K4: W^T bf16 packed
// ---------------------------------------------------------------------------
__global__ __launch_bounds__(256) void wt_kernel(const float* __restrict__ W,
                                                 uint* __restrict__ wt) {
    int idx = blockIdx.x * 256 + threadIdx.x;
    if (idx >= NF * NF / 2) return;
    int nrow = idx >> 6;
    int k2 = idx & 63;
    float a = W[(2 * k2) * NF + nrow];
    float b = W[(2 * k2 + 1) * NF + nrow];
    wt[idx] = (uint)f2bf(a) | ((uint)f2bf(b) << 16);
}

// ---------------------------------------------------------------------------
// Three-phase parallel exclusive scan of deg_in
// ---------------------------------------------------------------------------
__global__ __launch_bounds__(1024) void scan_sum_kernel(const int* __restrict__ deg,
                                                        int* __restrict__ bsum, int n) {
    int i = blockIdx.x * 1024 + threadIdx.x;
    int v = (i < n) ? deg[i] : 0;
#pragma unroll
    for (int off = 32; off >= 1; off >>= 1) v += __shfl_down(v, off, 64);
    __shared__ int ws[16];
    int wv = threadIdx.x >> 6, lane = threadIdx.x & 63;
    if (lane == 0) ws[wv] = v;
    __syncthreads();
    if (threadIdx.x == 0) {
        int s = 0;
#pragma unroll
        for (int k = 0; k < 16; ++k) s += ws[k];
        bsum[blockIdx.x] = s;
    }
}

__global__ __launch_bounds__(1024) void scan_bsum_kernel(int* __restrict__ bsum, int nb) {
    __shared__ int s[1024];
    int v = (threadIdx.x < (unsigned)nb) ? bsum[threadIdx.x] : 0;
    s[threadIdx.x] = v;
    __syncthreads();
    for (int off = 1; off < 1024; off <<= 1) {
        int t = (threadIdx.x >= (unsigned)off) ? s[threadIdx.x - off] : 0;
        __syncthreads();
        s[threadIdx.x] += t;
        __syncthreads();
    }
    if (threadIdx.x < (unsigned)nb) bsum[threadIdx.x] = s[threadIdx.x] - v;
}

__global__ __launch_bounds__(1024) void scan_final_kernel(const int* __restrict__ deg,
                                                          const int* __restrict__ bsum,
                                                          int* __restrict__ start,
                                                          int* __restrict__ cursor, int n) {
    int i = blockIdx.x * 1024 + threadIdx.x;
    int v = (i < n) ? deg[i] : 0;
    int lane = threadIdx.x & 63, wv = threadIdx.x >> 6;
    int incl = v;
#pragma unroll
    for (int off = 1; off < 64; off <<= 1) {
        int t = __shfl_up(incl, off, 64);
        if (lane >= off) incl += t;
    }
    __shared__ int ws[16];
    __shared__ int wo[16];
    if (lane == 63) ws[wv] = incl;
    __syncthreads();
    if (threadIdx.x == 0) {
        int s = 0;
#pragma unroll
        for (int k = 0; k < 16; ++k) { wo[k] = s; s += ws[k]; }
    }
    __syncthreads();
    int excl = incl - v + wo[wv] + bsum[blockIdx.x];
    if (i < n) { start[i] = excl; cursor[i] = excl; }
}

// ---------------------------------------------------------------------------
// K5: CSR fill (global atomics — next round's target)
// ---------------------------------------------------------------------------
__global__ __launch_bounds__(256) void fill_kernel(const int* __restrict__ src,
                                                   const int* __restrict__ dst,
                                                   int* __restrict__ cursor,
                                                   int* __restrict__ csr_src,
                                                   int n_edges) {
    int e = blockIdx.x * 256 + threadIdx.x;
    if (e < n_edges) {
        int d = dst[e];
        int pos = atomicAdd(&cursor[d], 1);
        csr_src[pos] = src[e];
    }
}

// ---------------------------------------------------------------------------
// K6: gather-aggregate (bf16), unroll-4: 4 independent 256B row loads in
// flight per wave; two accumulator pairs to shorten add chains.
// ---------------------------------------------------------------------------
__global__ __launch_bounds__(256) void gather_kernel(const uint* __restrict__ featn,
                                                     const int* __restrict__ csr_src,
                                                     const int* __restrict__ start,
                                                     const int* __restrict__ endp,
                                                     uint* __restrict__ rst_h,
                                                     int n_nodes) {
    int wid  = (blockIdx.x * 256 + threadIdx.x) >> 6;
    int lane = threadIdx.x & 63;
    if (wid >= n_nodes) return;
    int beg = start[wid];
    int end = endp[wid];
    float ax0 = 0.0f, ay0 = 0.0f, ax1 = 0.0f, ay1 = 0.0f;
    int i = beg;
    for (; i + 3 < end; i += 4) {
        int s0 = csr_src[i];
        int s1 = csr_src[i + 1];
        int s2 = csr_src[i + 2];
        int s3 = csr_src[i + 3];
        uint v0 = featn[(size_t)s0 * 64 + lane];
        uint v1 = featn[(size_t)s1 * 64 + lane];
        uint v2 = featn[(size_t)s2 * 64 + lane];
        uint v3 = featn[(size_t)s3 * 64 + lane];
        ax0 += bflo(v0); ay0 += bfhi(v0);
        ax1 += bflo(v1); ay1 += bfhi(v1);
        ax0 += bflo(v2); ay0 += bfhi(v2);
        ax1 += bflo(v3); ay1 += bfhi(v3);
    }
    for (; i < end; ++i) {
        int s = csr_src[i];
        uint v = featn[(size_t)s * 64 + lane];
        ax0 += bflo(v); ay0 += bfhi(v);
    }
    float ax = ax0 + ax1, ay = ay0 + ay1;
    rst_h[(size_t)wid * 64 + lane] = (uint)f2bf(ax) | ((uint)f2bf(ay) << 16);
}

// ---------------------------------------------------------------------------
// K7: out = relu(rst_h @ W + bias) via mfma_f32_16x16x32_bf16 (no LDS)
// ---------------------------------------------------------------------------
__global__ __launch_bounds__(256) void gemm_mfma_kernel(const ushort* __restrict__ rst_h,
                                                        const ushort* __restrict__ wt_h,
                                                        const float* __restrict__ bias,
                                                        float* __restrict__ out,
                                                        int n_nodes) {
    int wave = threadIdx.x >> 6;
    int lane = threadIdx.x & 63;
    int row0 = blockIdx.x * 64 + wave * 16;
    if (row0 >= n_nodes) return;
    int l16 = lane & 15, lq = lane >> 4;

    short8 a[4];
    const ushort* ap = rst_h + (size_t)(row0 + l16) * NF + lq * 8;
#pragma unroll
    for (int kt = 0; kt < 4; ++kt) a[kt] = *(const short8*)(ap + kt * 32);

#pragma unroll
    for (int nt = 0; nt < 8; ++nt) {
        f32x4 acc = {0.0f, 0.0f, 0.0f, 0.0f};
        const ushort* bp = wt_h + (size_t)(nt * 16 + l16) * NF + lq * 8;
#pragma unroll
        for (int kt = 0; kt < 4; ++kt) {
            short8 b = *(const short8*)(bp + kt * 32);
            acc = __builtin_amdgcn_mfma_f32_16x16x32_bf16(a[kt], b, acc, 0, 0, 0);
        }
        int col = nt * 16 + l16;
        float bv = bias[col];
#pragma unroll
        for (int r = 0; r < 4; ++r) {
            int orow = row0 + lq * 4 + r;
            if (orow < n_nodes) {
                float v = acc[r] + bv;
                out[(size_t)orow * NF + col] = v > 0.0f ? v : 0.0f;
            }
        }
    }
}

extern "C" void kernel_launch(void* const* d_in, const int* in_sizes, int n_in,
                              void* d_out, int out_size, void* d_ws, size_t ws_size,
                              hipStream_t stream) {
    const float* feat = (const float*)d_in[0];
    const float* W    = (const float*)d_in[1];
    const float* bias = (const float*)d_in[2];
    const int*   src  = (const int*)d_in[3];
    const int*   dst  = (const int*)d_in[4];

    int n_nodes = in_sizes[0] / NF;
    int n_edges = in_sizes[3];

    // ws: [rst_h n*64 u32][featn n*64 u32][deg_in n][deg_out n][norm n f32]
    //     [start n][cursor n][bsum 1024][wt 8192 u32][csr_src E]
    char* ws = (char*)d_ws;
    size_t row_u32 = (size_t)n_nodes * 64;
    uint*  rst_h   = (uint*)ws;
    uint*  featn   = rst_h + row_u32;
    int*   deg_in  = (int*)(featn + row_u32);
    int*   deg_out = deg_in + n_nodes;
    float* norm    = (float*)(deg_out + n_nodes);
    int*   start   = (int*)(norm + n_nodes);
    int*   cursor  = start + n_nodes;
    int*   bsum    = cursor + n_nodes;
    uint*  wt      = (uint*)(bsum + 1024);
    int*   csr_src = (int*)(wt + NF * NF / 2);

    int nwords = (n_nodes + 1) / 2;
    if (nwords <= NNW_MAX && (size_t)2 * NCHUNK * nwords <= row_u32 + 64) {
        // partials alias rst_h (written only by gather, long after degnorm)
        uint* partial_in  = rst_h;
        uint* partial_out = rst_h + (size_t)NCHUNK * nwords;
        int epb = (n_edges + NCHUNK - 1) / NCHUNK;
        hist_kernel<<<dim3(NCHUNK, 2), HIST_THREADS, 0, stream>>>(
            src, dst, partial_in, partial_out, n_edges, nwords, epb);
        degnorm_kernel<<<(nwords + 255) / 256, 256, 0, stream>>>(
            partial_in, partial_out, deg_in, norm, nwords, n_nodes);
    } else {
        hipMemsetAsync(deg_in, 0, 2 * (size_t)n_nodes * sizeof(int), stream);
        deg_kernel<<<(n_edges + 255) / 256, 256, 0, stream>>>(src, dst, deg_out, deg_in, n_edges);
        norm_kernel<<<(n_nodes + 255) / 256, 256, 0, stream>>>(deg_out, deg_in, norm, n_nodes);
    }

    int total_pairs = n_nodes * 64;
    featn_kernel<<<(total_pairs + 255) / 256, 256, 0, stream>>>(feat, norm, featn, total_pairs);
    wt_kernel<<<(NF * NF / 2 + 255) / 256, 256, 0, stream>>>(W, wt);

    int nb = (n_nodes + 1023) / 1024;
    scan_sum_kernel<<<nb, 1024, 0, stream>>>(deg_in, bsum, n_nodes);
    scan_bsum_kernel<<<1, 1024, 0, stream>>>(bsum, nb);
    scan_final_kernel<<<nb, 1024, 0, stream>>>(deg_in, bsum, start, cursor, n_nodes);

    fill_kernel<<<(n_edges + 255) / 256, 256, 0, stream>>>(src, dst, cursor, csr_src, n_edges);
    gather_kernel<<<(n_nodes * 64 + 255) / 256, 256, 0, stream>>>(featn, csr_src, start,
                                                                  cursor, rst_h, n_nodes);
    gemm_mfma_kernel<<<(n_nodes + 63) / 64, 256, 0, stream>>>((const ushort*)rst_h,
                                                              (const ushort*)wt, bias,
                                                              (float*)d_out, n_nodes);
}